// Round 1
// baseline (2253.982 us; speedup 1.0000x reference)
//
#include <hip/hip_runtime.h>
#include <math.h>

// ---------------- problem constants ----------------
#define NI   100000      // instances (patches)
#define DD   512         // feature dim
#define DA   256         // attention dim
#define KSEL 1000        // 1% of N for all top-k selections
#define NCOL 544         // packed GEMM columns: 256 Wa | 256 Wb | 4 Wcls | 15 Wr | 13 pad

// ---------------- d_out layout (floats) ----------------
#define OUT_FS   0         // final_score [N,4]
#define OUT_YP   400000    // Y_prob [4]
#define OUT_YH   400004    // Y_hat [1] (stored as float)
#define OUT_REF  400005    // ref_score [N,5]
#define OUT_LOSS 900005    // instance_loss [1]

// ---------------- workspace layout (float offsets) ----------------
#define OFF_DET    0                        // det_logit  N*4
#define OFF_CLS    (OFF_DET + NI*4)         // cls_score  N*4
#define OFF_REF0   (OFF_CLS + NI*4)         // softmax(h@Wr0+br0) N*5
#define OFF_REF1   (OFF_REF0 + NI*5)        // softmax(h@Wr1+br1) N*5
#define OFF_MEAN   (OFF_REF1 + NI*5)        // mean_score N
#define OFF_WPACK  (OFF_MEAN + NI)          // packed W [512][544]
#define OFF_BPACK  (OFF_WPACK + DD*NCOL)    // packed bias [544]
#define OFF_SCAL   (OFF_BPACK + NCOL)       // 64 scalar slots (see kernel_launch)
#define OFF_SELIDX (OFF_SCAL + 64)          // selected indices 15*1000 ints

// monotonic float<->uint key (total order, handles sign)
__device__ __forceinline__ unsigned fenc(float x) {
    unsigned u = __float_as_uint(x);
    return (u & 0x80000000u) ? ~u : (u | 0x80000000u);
}
__device__ __forceinline__ float fdec(unsigned u) {
    unsigned b = (u & 0x80000000u) ? (u & 0x7FFFFFFFu) : ~u;
    return __uint_as_float(b);
}

// ================= kernel 1: pack weights / biases, init scalar accumulators =================
__global__ void prep_kernel(const float* __restrict__ Wa, const float* __restrict__ Wb,
                            const float* __restrict__ Wcls, const float* __restrict__ Wr,
                            const float* __restrict__ ba, const float* __restrict__ bb,
                            const float* __restrict__ bcls, const float* __restrict__ br,
                            float* __restrict__ ws)
{
    const int idx = blockIdx.x * blockDim.x + threadIdx.x;
    if (idx < DD * NCOL) {
        const int k = idx / NCOL, col = idx % NCOL;
        float v = 0.f;
        if (col < 256)       v = Wa[k * 256 + col];
        else if (col < 512)  v = Wb[k * 256 + (col - 256)];
        else if (col < 516)  v = Wcls[k * 4 + (col - 512)];
        else if (col < 531) { const int q = col - 516; v = Wr[((q / 5) * DD + k) * 5 + (q % 5)]; }
        ws[OFF_WPACK + idx] = v;
    }
    if (idx < NCOL) {
        float v = 0.f;
        if (idx < 256)       v = ba[idx];
        else if (idx < 512)  v = bb[idx - 256];
        else if (idx < 516)  v = bcls[idx - 512];
        else if (idx < 531)  v = br[idx - 516];   // br is [3][5] contiguous
        ws[OFF_BPACK + idx] = v;
    }
    if (idx < 64) {
        // slots 12..15 = fs_min_enc -> init 0xFFFFFFFF, everything else 0
        unsigned* su = (unsigned*)(ws + OFF_SCAL);
        su[idx] = (idx >= 12 && idx < 16) ? 0xFFFFFFFFu : 0u;
    }
}

// ================= kernel 2: fused GEMM [64 inst x 544 cols x K=512] + epilogue =================
// cols 0..255 = h@Wa, 256..511 = h@Wb (gated -> det_logit via Wc), 512..515 = cls logits,
// 516..530 = Wr logits (-> ref softmaxes; r=2 written straight to d_out).
__global__ __launch_bounds__(512) void gemm_fused(
    const float* __restrict__ h, const float* __restrict__ wpack,
    const float* __restrict__ bpack, const float* __restrict__ Wc,
    const float* __restrict__ bc,
    float* __restrict__ det_logit, float* __restrict__ cls_score,
    float* __restrict__ ref0, float* __restrict__ ref1,
    float* __restrict__ out_ref2, unsigned* __restrict__ det_max_enc)
{
    __shared__ float sh[16][64];       // h tile, k-major
    __shared__ float sw[16][NCOL];     // W tile
    __shared__ float sWc[DA * 4];
    __shared__ float sbias[NCOL];
    __shared__ float slog[64][20];     // 19 small-column logits per instance
    __shared__ float sdet[64][4];

    const int tid = threadIdx.x;
    const int cg  = tid & 31;          // column group 0..31
    const int im  = tid >> 5;          // instance group 0..15 (4 instances each)
    const int i0  = blockIdx.x * 64;

    for (int t = tid; t < DA * 4; t += 512) sWc[t] = Wc[t];
    for (int t = tid; t < NCOL; t += 512)   sbias[t] = bpack[t];

    float acc[17][4];                  // [col j][instance ii], col = cg + 32*j
    #pragma unroll
    for (int j = 0; j < 17; ++j)
        #pragma unroll
        for (int ii = 0; ii < 4; ++ii) acc[j][ii] = 0.f;

    for (int kc = 0; kc < DD; kc += 16) {
        for (int idx = tid; idx < 16 * 136; idx += 512) {
            const int row = idx / 136, c4 = idx % 136;
            *(float4*)&sw[row][c4 * 4] = *(const float4*)&wpack[(size_t)(kc + row) * NCOL + c4 * 4];
        }
        if (tid < 256) {
            const int il = tid >> 2, kq = tid & 3;
            const int gi = i0 + il;
            float4 v = make_float4(0.f, 0.f, 0.f, 0.f);
            if (gi < NI) v = *(const float4*)&h[(size_t)gi * DD + kc + kq * 4];
            sh[kq * 4 + 0][il] = v.x; sh[kq * 4 + 1][il] = v.y;
            sh[kq * 4 + 2][il] = v.z; sh[kq * 4 + 3][il] = v.w;
        }
        __syncthreads();
        #pragma unroll 4
        for (int k = 0; k < 16; ++k) {
            const float4 hv = *(const float4*)&sh[k][im * 4];
            float wv[17];
            #pragma unroll
            for (int j = 0; j < 17; ++j) wv[j] = sw[k][cg + 32 * j];
            #pragma unroll
            for (int j = 0; j < 17; ++j) {
                acc[j][0] += wv[j] * hv.x; acc[j][1] += wv[j] * hv.y;
                acc[j][2] += wv[j] * hv.z; acc[j][3] += wv[j] * hv.w;
            }
        }
        __syncthreads();
    }

    // ---- epilogue: gated attention -> det partials ----
    float det[4][4];                   // [instance ii][class c]
    #pragma unroll
    for (int ii = 0; ii < 4; ++ii)
        #pragma unroll
        for (int c = 0; c < 4; ++c) det[ii][c] = 0.f;

    #pragma unroll
    for (int j = 0; j < 8; ++j) {
        const int col = cg + 32 * j;   // 0..255; paired Wb col is col+256 = j+8 in this thread
        const float wc0 = sWc[col*4+0], wc1 = sWc[col*4+1], wc2 = sWc[col*4+2], wc3 = sWc[col*4+3];
        const float bA = sbias[col], bB = sbias[col + 256];
        #pragma unroll
        for (int ii = 0; ii < 4; ++ii) {
            const float a = tanhf(acc[j][ii] + bA);
            const float s = acc[j + 8][ii] + bB;
            const float bsig = 1.f / (1.f + expf(-s));
            const float g = a * bsig;
            det[ii][0] += g * wc0; det[ii][1] += g * wc1;
            det[ii][2] += g * wc2; det[ii][3] += g * wc3;
        }
    }
    // reduce over the 32 column-groups (lanes of a 32-half share one im)
    #pragma unroll
    for (int m = 1; m < 32; m <<= 1)
        #pragma unroll
        for (int ii = 0; ii < 4; ++ii)
            #pragma unroll
            for (int c = 0; c < 4; ++c) det[ii][c] += __shfl_xor(det[ii][c], m, 64);
    if (cg == 0) {
        #pragma unroll
        for (int ii = 0; ii < 4; ++ii)
            #pragma unroll
            for (int c = 0; c < 4; ++c) sdet[im * 4 + ii][c] = det[ii][c];
    }
    if (cg < 19) {
        #pragma unroll
        for (int ii = 0; ii < 4; ++ii) slog[im * 4 + ii][cg] = acc[16][ii] + sbias[512 + cg];
    }
    __syncthreads();

    // det_logit write + per-class block max -> global encoded atomicMax
    if (tid < 256) {
        const int il = tid >> 2, c = tid & 3;
        const int gi = i0 + il;
        const float val = sdet[il][c] + bc[c];
        float mval = (gi < NI) ? val : -3.4e38f;
        if (gi < NI) det_logit[(size_t)gi * 4 + c] = val;
        #pragma unroll
        for (int m = 4; m < 64; m <<= 1) mval = fmaxf(mval, __shfl_xor(mval, m, 64));
        if ((tid & 63) < 4) atomicMax(&det_max_enc[tid & 3], fenc(mval));
    }

    // per-instance softmaxes of the 19 small columns
    if (tid < 64) {
        const int gi = i0 + tid;
        if (gi < NI) {
            float L[19];
            #pragma unroll
            for (int q = 0; q < 19; ++q) L[q] = slog[tid][q];
            {   // cls softmax over cols 0..3
                float m = fmaxf(fmaxf(L[0], L[1]), fmaxf(L[2], L[3]));
                float e0 = expf(L[0]-m), e1 = expf(L[1]-m), e2 = expf(L[2]-m), e3 = expf(L[3]-m);
                const float inv = 1.f / (e0 + e1 + e2 + e3);
                cls_score[(size_t)gi*4+0] = e0*inv; cls_score[(size_t)gi*4+1] = e1*inv;
                cls_score[(size_t)gi*4+2] = e2*inv; cls_score[(size_t)gi*4+3] = e3*inv;
            }
            #pragma unroll
            for (int r = 0; r < 3; ++r) {   // ref softmaxes over cols 4+5r..8+5r
                float m = L[4+5*r];
                #pragma unroll
                for (int e = 1; e < 5; ++e) m = fmaxf(m, L[4+5*r+e]);
                float ev[5]; float s = 0.f;
                #pragma unroll
                for (int e = 0; e < 5; ++e) { ev[e] = expf(L[4+5*r+e] - m); s += ev[e]; }
                const float inv = 1.f / s;
                float* dst = (r == 0) ? ref0 : ((r == 1) ? ref1 : out_ref2);
                #pragma unroll
                for (int e = 0; e < 5; ++e) dst[(size_t)gi*5+e] = ev[e] * inv;
            }
        }
    }
}

// ================= kernel 3: det softmax denominator =================
__global__ __launch_bounds__(256) void det_sum_kernel(const float* __restrict__ det_logit,
        const unsigned* __restrict__ det_max_enc, float* __restrict__ det_sumexp)
{
    __shared__ float wsum[4][4];
    const int i = blockIdx.x * 256 + threadIdx.x;
    float p[4] = {0.f, 0.f, 0.f, 0.f};
    if (i < NI) {
        #pragma unroll
        for (int c = 0; c < 4; ++c) p[c] = expf(det_logit[(size_t)i*4+c] - fdec(det_max_enc[c]));
    }
    #pragma unroll
    for (int c = 0; c < 4; ++c)
        #pragma unroll
        for (int m = 1; m < 64; m <<= 1) p[c] += __shfl_xor(p[c], m, 64);
    const int w = threadIdx.x >> 6;
    if ((threadIdx.x & 63) == 0) {
        #pragma unroll
        for (int c = 0; c < 4; ++c) wsum[w][c] = p[c];
    }
    __syncthreads();
    if (threadIdx.x < 4) {
        const int c = threadIdx.x;
        atomicAdd(&det_sumexp[c], wsum[0][c] + wsum[1][c] + wsum[2][c] + wsum[3][c]);
    }
}

// ================= kernel 4: final_score, mean_score, Y_prob partials, per-class min/max =================
__global__ __launch_bounds__(256) void final_kernel(const float* __restrict__ det_logit,
        const float* __restrict__ cls_score, const unsigned* __restrict__ det_max_enc,
        const float* __restrict__ det_sumexp, float* __restrict__ out_fs,
        float* __restrict__ mean_sc, float* __restrict__ yprob_sum,
        unsigned* __restrict__ fs_min_enc, unsigned* __restrict__ fs_max_enc)
{
    __shared__ float ssum[4][4], smin[4][4], smax[4][4];
    const int i = blockIdx.x * 256 + threadIdx.x;
    const bool valid = i < NI;
    float f[4]; float tot = 0.f;
    #pragma unroll
    for (int c = 0; c < 4; ++c) {
        float v = 0.f;
        if (valid) {
            const float ds = expf(det_logit[(size_t)i*4+c] - fdec(det_max_enc[c])) / det_sumexp[c];
            v = cls_score[(size_t)i*4+c] * ds;
            out_fs[(size_t)i*4+c] = v;
        }
        f[c] = v; tot += v;
    }
    if (valid) mean_sc[i] = 0.25f * tot;
    float sm[4], mn[4], mx[4];
    #pragma unroll
    for (int c = 0; c < 4; ++c) {
        sm[c] = f[c];
        mn[c] = valid ? f[c] : 3.4e38f;
        mx[c] = valid ? f[c] : -3.4e38f;
    }
    #pragma unroll
    for (int c = 0; c < 4; ++c)
        #pragma unroll
        for (int m = 1; m < 64; m <<= 1) {
            sm[c] += __shfl_xor(sm[c], m, 64);
            mn[c] = fminf(mn[c], __shfl_xor(mn[c], m, 64));
            mx[c] = fmaxf(mx[c], __shfl_xor(mx[c], m, 64));
        }
    const int w = threadIdx.x >> 6;
    if ((threadIdx.x & 63) == 0) {
        #pragma unroll
        for (int c = 0; c < 4; ++c) { ssum[w][c] = sm[c]; smin[w][c] = mn[c]; smax[w][c] = mx[c]; }
    }
    __syncthreads();
    if (threadIdx.x < 4) {
        const int c = threadIdx.x;
        float S = 0.f, MN = 3.4e38f, MX = -3.4e38f;
        #pragma unroll
        for (int w2 = 0; w2 < 4; ++w2) {
            S += ssum[w2][c]; MN = fminf(MN, smin[w2][c]); MX = fmaxf(MX, smax[w2][c]);
        }
        atomicAdd(&yprob_sum[c], S);
        atomicMin(&fs_min_enc[c], fenc(MN));
        atomicMax(&fs_max_enc[c], fenc(MX));
    }
}

// ================= kernel 5: Y_prob/Y_hat + selection thresholds + in_label =================
__global__ void scalars_kernel(const float* __restrict__ yprob_sum, const unsigned* __restrict__ fs_min_enc,
                               const unsigned* __restrict__ fs_max_enc, const int* __restrict__ label,
                               float* __restrict__ out, float* __restrict__ half_thr, int* __restrict__ incl)
{
    if (blockIdx.x == 0 && threadIdx.x == 0) {
        float best = -1.f; int arg = 0;
        for (int c = 0; c < 4; ++c) {
            float v = yprob_sum[c];
            v = fminf(fmaxf(v, 1e-10f), 1.f - 1e-10f);
            out[OUT_YP + c] = v;
            if (v > best) { best = v; arg = c; }
        }
        out[OUT_YH] = (float)arg;
        for (int c = 0; c < 4; ++c) {
            const float mn = fdec(fs_min_enc[c]);
            const float mx = fdec(fs_max_enc[c]);
            half_thr[c] = mn + 0.5f * (mx - mn);   // norm>0.5  <=>  fs > this
        }
        const int l0 = label[0], l1 = label[1];
        for (int c = 0; c < 4; ++c) incl[c] = (l0 == c || l1 == c) ? 1 : 0;
        incl[4] = 1;   // bg class always included in ref losses
    }
}

// ================= kernel 6: 15 top-k column selections (one block per column) =================
// b 0..3: TP on final_score col b (k=1000, val > norm-0.5 thr), b=4: NP bottom-k of mean (val<0.5),
// b 5..9: ref0 cols 0..4 (val>0.5), b 10..14: ref1 cols 0..4 (val>0.5).
__global__ __launch_bounds__(1024) void select_kernel(
    const float* __restrict__ out_fs, const float* __restrict__ mean_sc,
    const float* __restrict__ ref0, const float* __restrict__ ref1,
    const float* __restrict__ half_thr, const int* __restrict__ incl,
    int* __restrict__ sel_idx, int* __restrict__ sel_cnt)
{
    const int b = blockIdx.x;
    const float* base; int stride; int bottom = 0; float extra;
    if (b < 4) {
        if (!incl[b]) return;
        base = out_fs + b; stride = 4; extra = half_thr[b];
    } else if (b == 4) {
        base = mean_sc; stride = 1; bottom = 1; extra = 0.5f;
    } else if (b < 10) {
        const int c = b - 5; if (c < 4 && !incl[c]) return;
        base = ref0 + c; stride = 5; extra = 0.5f;
    } else {
        const int c = b - 10; if (c < 4 && !incl[c]) return;
        base = ref1 + c; stride = 5; extra = 0.5f;
    }
    __shared__ unsigned s_bound[2];
    __shared__ int wcnt[16];
    unsigned lo = 0u, hi = 0xFFFFFFFFu;   // invariant: count(u>=lo)>=K, count(u>=hi)<K
    while (hi - lo > 1u) {
        const unsigned mid = lo + ((hi - lo) >> 1);
        int cnt = 0;
        for (int i = threadIdx.x; i < NI; i += 1024) {
            const float v = base[(size_t)i * stride];
            const unsigned u = fenc(bottom ? -v : v);
            cnt += (u >= mid) ? 1 : 0;
        }
        #pragma unroll
        for (int m = 1; m < 64; m <<= 1) cnt += __shfl_xor(cnt, m, 64);
        if ((threadIdx.x & 63) == 0) wcnt[threadIdx.x >> 6] = cnt;
        __syncthreads();
        if (threadIdx.x == 0) {
            int t = 0;
            for (int q = 0; q < 16; ++q) t += wcnt[q];
            if (t >= KSEL) s_bound[0] = mid; else s_bound[1] = mid;
            if (t >= KSEL) { } // keep branchless-ish
        }
        __syncthreads();
        if (threadIdx.x == 0) { /* already stored */ }
        lo = (hi - lo > 1u) ? lo : lo; // no-op to keep structure clear
        // re-read updated bound
        unsigned nlo = lo, nhi = hi;
        if (true) {
            // one of the two bounds moved to mid
            __syncthreads();
            nlo = lo; nhi = hi;
        }
        // simple approach: thread0 stored into s_bound; distribute:
        if (threadIdx.x == 0) { wcnt[0] = 0; }
        __syncthreads();
        // s_bound[0]/s_bound[1] hold candidate updates only for the side that moved;
        // recompute locally from whichever slot was written this iteration:
        // To stay simple and correct, thread0 wrote exactly one slot; mirror both:
        if (threadIdx.x == 0) { s_bound[0] = s_bound[0]; s_bound[1] = s_bound[1]; }
        __syncthreads();
        // initialize untouched slot on first iteration
        lo = s_bound[0]; hi = s_bound[1];
        if (lo == 0u && hi == 0u) { /* unreachable */ }
        __syncthreads();
        // Guard: on the first iteration one slot may be uninitialized; fix by bounds
        if (hi <= lo) { if (s_bound[0] != 0u || true) { /* fallthrough */ } }
        if (hi == 0u) hi = 0xFFFFFFFFu;      // slot never written yet
        if (lo > hi) lo = 0u;
    }
    const unsigned ustar = lo;
    for (int i = threadIdx.x; i < NI; i += 1024) {
        const float v = base[(size_t)i * stride];
        const unsigned u = fenc(bottom ? -v : v);
        const bool pass = (u >= ustar) && (bottom ? (v < extra) : (v > extra));
        if (pass) {
            const int pos = atomicAdd(&sel_cnt[b], 1);
            if (pos < KSEL) sel_idx[b * KSEL + pos] = i;
        }
    }
}

// ================= kernel 7: CE over selected candidates (one wave per candidate slot) =================
__global__ __launch_bounds__(256) void ce_kernel(const float* __restrict__ h, const float* __restrict__ Wr,
                                                 const float* __restrict__ br, const int* __restrict__ sel_idx,
                                                 const int* __restrict__ sel_cnt, float* __restrict__ num_acc)
{
    const int lane = threadIdx.x & 63;
    const int wid = (blockIdx.x * blockDim.x + threadIdx.x) >> 6;
    const int nw = (gridDim.x * blockDim.x) >> 6;
    float l0a = 0.f, l1a = 0.f, l2a = 0.f;
    for (int slot = wid; slot < 15 * KSEL; slot += nw) {
        const int b = slot / KSEL;
        const int j = slot - b * KSEL;
        const int cnt = min(sel_cnt[b], KSEL);
        if (j >= cnt) continue;
        const int i = sel_idx[b * KSEL + j];
        const int g = (b < 5) ? 0 : ((b < 10) ? 1 : 2);
        const int tgt = (b < 4) ? b : ((b == 4) ? 4 : ((b < 10) ? (b - 5) : (b - 10)));
        const float* hr = h + (size_t)i * DD;
        const float* wr = Wr + (size_t)g * DD * 5;
        const int d0 = lane * 8;
        const float4 va = *(const float4*)&hr[d0];
        const float4 vb = *(const float4*)&hr[d0 + 4];
        const float hv[8] = {va.x, va.y, va.z, va.w, vb.x, vb.y, vb.z, vb.w};
        float acc[5] = {0.f, 0.f, 0.f, 0.f, 0.f};
        #pragma unroll
        for (int t = 0; t < 8; ++t) {
            const float* row = wr + (size_t)(d0 + t) * 5;
            #pragma unroll
            for (int e = 0; e < 5; ++e) acc[e] += hv[t] * row[e];
        }
        #pragma unroll
        for (int e = 0; e < 5; ++e)
            #pragma unroll
            for (int m = 1; m < 64; m <<= 1) acc[e] += __shfl_xor(acc[e], m, 64);
        if (lane == 0) {
            float l[5];
            #pragma unroll
            for (int e = 0; e < 5; ++e) l[e] = acc[e] + br[g * 5 + e];
            float mx = l[0];
            #pragma unroll
            for (int e = 1; e < 5; ++e) mx = fmaxf(mx, l[e]);
            float s = 0.f;
            #pragma unroll
            for (int e = 0; e < 5; ++e) s += expf(l[e] - mx);
            const float ce = logf(s) + mx - l[tgt];
            if (g == 0) l0a += ce; else if (g == 1) l1a += ce; else l2a += ce;
        }
    }
    if (lane == 0) {
        if (l0a != 0.f) atomicAdd(&num_acc[0], l0a);
        if (l1a != 0.f) atomicAdd(&num_acc[1], l1a);
        if (l2a != 0.f) atomicAdd(&num_acc[2], l2a);
    }
}

// ================= kernel 8: finalize instance_loss =================
__global__ void loss_kernel(const float* __restrict__ num_acc, const int* __restrict__ sel_cnt,
                            float* __restrict__ out)
{
    if (blockIdx.x == 0 && threadIdx.x == 0) {
        float loss = 0.f;
        for (int g = 0; g < 3; ++g) {
            int den = 0;
            for (int b = g * 5; b < g * 5 + 5; ++b) den += min(sel_cnt[b], KSEL);
            loss += num_acc[g] / (float)(den > 1 ? den : 1);
        }
        out[OUT_LOSS] = loss;
    }
}

// ================= launch =================
extern "C" void kernel_launch(void* const* d_in, const int* in_sizes, int n_in,
                              void* d_out, int out_size, void* d_ws, size_t ws_size,
                              hipStream_t stream)
{
    const float* h    = (const float*)d_in[0];
    const int*   lab  = (const int*)d_in[1];
    const float* Wa   = (const float*)d_in[2];
    const float* ba   = (const float*)d_in[3];
    const float* Wb   = (const float*)d_in[4];
    const float* bb   = (const float*)d_in[5];
    const float* Wc   = (const float*)d_in[6];
    const float* bc   = (const float*)d_in[7];
    const float* Wcls = (const float*)d_in[8];
    const float* bcls = (const float*)d_in[9];
    const float* Wr   = (const float*)d_in[10];
    const float* br   = (const float*)d_in[11];
    float* out = (float*)d_out;
    float* ws  = (float*)d_ws;

    unsigned* su = (unsigned*)(ws + OFF_SCAL);
    float*    sf = (float*)(ws + OFF_SCAL);
    int*      si = (int*)(ws + OFF_SCAL);

    float* det_logit = ws + OFF_DET;
    float* cls_score = ws + OFF_CLS;
    float* ref0      = ws + OFF_REF0;
    float* ref1      = ws + OFF_REF1;
    float* mean_sc   = ws + OFF_MEAN;
    float* wpack     = ws + OFF_WPACK;
    float* bpack     = ws + OFF_BPACK;
    unsigned* det_max_enc = su + 0;
    float*    det_sumexp  = sf + 4;
    float*    yprob_sum   = sf + 8;
    unsigned* fs_min_enc  = su + 12;
    unsigned* fs_max_enc  = su + 16;
    float*    half_thr    = sf + 20;
    int*      incl        = si + 24;
    float*    num_acc     = sf + 29;
    int*      sel_cnt     = si + 32;
    int*      sel_idx     = (int*)(ws + OFF_SELIDX);
    (void)wpack; (void)bpack;

    hipLaunchKernelGGL(prep_kernel, dim3(1088), dim3(256), 0, stream,
                       Wa, Wb, Wcls, Wr, ba, bb, bcls, br, ws);
    hipLaunchKernelGGL(gemm_fused, dim3((NI + 63) / 64), dim3(512), 0, stream,
                       h, ws + OFF_WPACK, ws + OFF_BPACK, Wc, bc,
                       det_logit, cls_score, ref0, ref1, out + OUT_REF, det_max_enc);
    hipLaunchKernelGGL(det_sum_kernel, dim3((NI + 255) / 256), dim3(256), 0, stream,
                       det_logit, det_max_enc, det_sumexp);
    hipLaunchKernelGGL(final_kernel, dim3((NI + 255) / 256), dim3(256), 0, stream,
                       det_logit, cls_score, det_max_enc, det_sumexp,
                       out + OUT_FS, mean_sc, yprob_sum, fs_min_enc, fs_max_enc);
    hipLaunchKernelGGL(scalars_kernel, dim3(1), dim3(64), 0, stream,
                       yprob_sum, fs_min_enc, fs_max_enc, lab, out, half_thr, incl);
    hipLaunchKernelGGL(select_kernel, dim3(15), dim3(1024), 0, stream,
                       out + OUT_FS, mean_sc, ref0, ref1, half_thr, incl, sel_idx, sel_cnt);
    hipLaunchKernelGGL(ce_kernel, dim3(240), dim3(256), 0, stream,
                       h, Wr, br, sel_idx, sel_cnt, num_acc);
    hipLaunchKernelGGL(loss_kernel, dim3(1), dim3(64), 0, stream,
                       num_acc, sel_cnt, out);
}

// Round 2
// 1047.282 us; speedup vs baseline: 2.1522x; 2.1522x over previous
//
#include <hip/hip_runtime.h>
#include <math.h>

// ---------------- problem constants ----------------
#define NI    100000
#define KSEL  1000
#define NCOL2 640          // packed cols: 512 interleaved Wa/Wb pairs | 4 Wcls | 15 Wr | 109 pad

// ---------------- d_out layout (floats) ----------------
#define OUT_FS   0
#define OUT_YP   400000
#define OUT_YH   400004
#define OUT_REF  400005
#define OUT_LOSS 900005

// ---------------- workspace layout (float offsets) ----------------
#define OFF_DET    0                 // det_logit N*4 (init bc, atomic-accumulated)
#define OFF_CLS    400000            // cls_score N*4
#define OFF_REF0   800000            // softmax(h@Wr0+br0) N*5
#define OFF_REF1   1300000           // softmax(h@Wr1+br1) N*5
#define OFF_MEAN   1800000           // mean_score N
#define OFF_WPT    1900000           // bf16 packed W^T [640][512] = 327680 ushorts
#define OFF_BPACK  2063840           // packed bias [640]
#define OFF_SCAL   2064480           // 128 scalar slots
#define OFF_SELIDX 2064608           // 15*1000 ints
#define OFF_HIST   2079608           // 15*65536 u32 (reused for both radix levels)

// scalar slots (index into u32/f32/i32 view of ws+OFF_SCAL)
#define SC_SUMEXP 0     // f[4] det softmax denominator
#define SC_YPROB  4     // f[4]
#define SC_FSMIN  8     // u[4] encoded min of final_score per class
#define SC_FSMAX  12    // u[4]
#define SC_THR    16    // f[4] norm-0.5 threshold on raw fs
#define SC_INCL   20    // i[5]
#define SC_NUM    25    // f[3] CE numerators
#define SC_CNT    28    // i[15] selected counts
#define SC_BUCKA  43    // u[15] level-A bucket
#define SC_RESTK  58    // u[15] remaining k inside bucket
#define SC_KTHK   73    // u[15] exact k-th key

typedef short short8 __attribute__((ext_vector_type(8)));
typedef float f32x4 __attribute__((ext_vector_type(4)));

__device__ __forceinline__ unsigned fenc(float x) {
    unsigned u = __float_as_uint(x);
    return (u & 0x80000000u) ? ~u : (u | 0x80000000u);
}
__device__ __forceinline__ unsigned short f2bf(float f) {
    unsigned u = __float_as_uint(f);
    return (unsigned short)((u + 0x7FFFu + ((u >> 16) & 1u)) >> 16);
}

// ================= kernel 1: pack weights bf16 col-major, biases, init det/scalars/hist =================
__global__ __launch_bounds__(256) void prep_kernel(
    const float* __restrict__ Wa, const float* __restrict__ Wb,
    const float* __restrict__ Wcls, const float* __restrict__ Wr,
    const float* __restrict__ ba, const float* __restrict__ bb,
    const float* __restrict__ bcls, const float* __restrict__ br,
    const float* __restrict__ bc, float* __restrict__ ws)
{
    const int tid0 = blockIdx.x * 256 + threadIdx.x;   // grid 1280*256 = 327680 threads
    unsigned short* wpT = (unsigned short*)(ws + OFF_WPT);
    if (tid0 < NCOL2 * 512) {
        const int c = tid0 >> 9, k = tid0 & 511;
        float v = 0.f;
        if (c < 512)      { const int j = c >> 1; v = (c & 1) ? Wb[k*256 + j] : Wa[k*256 + j]; }
        else if (c < 516)   v = Wcls[k*4 + (c - 512)];
        else if (c < 531) { const int q = c - 516; v = Wr[((q/5)*512 + k)*5 + (q%5)]; }
        wpT[tid0] = f2bf(v);
    }
    if (tid0 < NCOL2) {
        float v = 0.f; const int c = tid0;
        if (c < 512)      v = (c & 1) ? bb[c >> 1] : ba[c >> 1];
        else if (c < 516) v = bcls[c - 512];
        else if (c < 531) v = br[c - 516];
        ws[OFF_BPACK + c] = v;
    }
    if (tid0 < 128) {
        unsigned* su = (unsigned*)(ws + OFF_SCAL);
        su[tid0] = (tid0 >= SC_FSMIN && tid0 < SC_FSMIN + 4) ? 0xFFFFFFFFu : 0u;
    }
    for (int i = tid0; i < NI * 4; i += 327680) ws[OFF_DET + i] = bc[i & 3];
    unsigned* hist = (unsigned*)(ws + OFF_HIST);
    for (int i = tid0; i < 15 * 65536; i += 327680) hist[i] = 0u;
}

// ================= kernel 2: bf16 MFMA GEMM 128x128 tiles, fused epilogue =================
// grid (5, 782): x = N-block (fast, L2 reuse of A rows), y = M-block.
// by<4: 64 gate pairs -> partial det_logit atomicAdd. by==4: cls/ref softmaxes.
__global__ __launch_bounds__(256) void gemm_mfma(
    const float* __restrict__ h, const unsigned short* __restrict__ wpT,
    const float* __restrict__ bpack, const float* __restrict__ Wc,
    float* __restrict__ det_logit, float* __restrict__ cls_score,
    float* __restrict__ ref0, float* __restrict__ ref1, float* __restrict__ out_ref2)
{
    __shared__ unsigned short Als[128 * 40];   // [row][32k + pad8] bf16
    __shared__ unsigned short Bls[128 * 40];   // [col][32k + pad8] bf16
    __shared__ float sbias_blk[128];
    __shared__ float sWcb[256];                // Wc rows for this block's 64 pairs
    __shared__ float slog[128 * 20];           // by==4: small-col logits

    const int tid = threadIdx.x;
    const int by  = blockIdx.x;
    const int bm0 = blockIdx.y * 128;
    const int n0  = by * 128;
    const int lane = tid & 63;
    const int w = tid >> 6;
    const int wm = (w >> 1) * 64, wn = (w & 1) * 64;
    const int lrow = lane & 15, lq = lane >> 4;

    if (by < 4 && tid < 256) sWcb[tid] = Wc[(n0 >> 1) * 4 + tid];
    if (tid < 128) sbias_blk[tid] = bpack[n0 + tid];

    f32x4 acc[4][4];
    #pragma unroll
    for (int mt = 0; mt < 4; ++mt)
        #pragma unroll
        for (int nt = 0; nt < 4; ++nt) acc[mt][nt] = (f32x4)0.f;

    float4 aR[4]; uint4 bR[2];
    #pragma unroll
    for (int it = 0; it < 4; ++it) {
        const int q = tid + it*256, row = q >> 3, k0 = (q & 7) * 4, grow = bm0 + row;
        aR[it] = (grow < NI) ? *(const float4*)&h[(size_t)grow * 512 + k0]
                             : make_float4(0.f, 0.f, 0.f, 0.f);
    }
    #pragma unroll
    for (int it = 0; it < 2; ++it) {
        const int q = tid + it*256, col = q >> 2, k0 = (q & 3) * 8;
        bR[it] = *(const uint4*)&wpT[(size_t)(n0 + col) * 512 + k0];
    }

    for (int kc = 0; kc < 512; kc += 32) {
        #pragma unroll
        for (int it = 0; it < 4; ++it) {
            const int q = tid + it*256, row = q >> 3, k0 = (q & 7) * 4;
            ushort4 pk;
            pk.x = f2bf(aR[it].x); pk.y = f2bf(aR[it].y);
            pk.z = f2bf(aR[it].z); pk.w = f2bf(aR[it].w);
            *(ushort4*)&Als[row * 40 + k0] = pk;
        }
        #pragma unroll
        for (int it = 0; it < 2; ++it) {
            const int q = tid + it*256, col = q >> 2, k0 = (q & 3) * 8;
            *(uint4*)&Bls[col * 40 + k0] = bR[it];
        }
        __syncthreads();
        const int kn = kc + 32;
        if (kn < 512) {   // prefetch next chunk (overlaps MFMA)
            #pragma unroll
            for (int it = 0; it < 4; ++it) {
                const int q = tid + it*256, row = q >> 3, k0 = (q & 7) * 4, grow = bm0 + row;
                aR[it] = (grow < NI) ? *(const float4*)&h[(size_t)grow * 512 + kn + k0]
                                     : make_float4(0.f, 0.f, 0.f, 0.f);
            }
            #pragma unroll
            for (int it = 0; it < 2; ++it) {
                const int q = tid + it*256, col = q >> 2, k0 = (q & 3) * 8;
                bR[it] = *(const uint4*)&wpT[(size_t)(n0 + col) * 512 + kn + k0];
            }
        }
        short8 af[4], bfr[4];
        #pragma unroll
        for (int mt = 0; mt < 4; ++mt) af[mt]  = *(const short8*)&Als[(wm + mt*16 + lrow) * 40 + lq*8];
        #pragma unroll
        for (int nt = 0; nt < 4; ++nt) bfr[nt] = *(const short8*)&Bls[(wn + nt*16 + lrow) * 40 + lq*8];
        #pragma unroll
        for (int mt = 0; mt < 4; ++mt)
            #pragma unroll
            for (int nt = 0; nt < 4; ++nt)
                acc[mt][nt] = __builtin_amdgcn_mfma_f32_16x16x32_bf16(af[mt], bfr[nt], acc[mt][nt], 0, 0, 0);
        __syncthreads();
    }

    if (by < 4) {
        // gated attention partial det_logit: C/D layout col=lane&15, row=lq*4+reg
        #pragma unroll
        for (int mt = 0; mt < 4; ++mt) {
            #pragma unroll
            for (int reg = 0; reg < 4; ++reg) {
                float c0 = 0.f, c1 = 0.f, c2 = 0.f, c3 = 0.f;
                #pragma unroll
                for (int nt = 0; nt < 4; ++nt) {
                    const int cl = wn + nt*16 + lrow;          // local col; parity == lane parity
                    const float v = acc[mt][nt][reg] + sbias_blk[cl];
                    const float p = __shfl_xor(v, 1);
                    const float ve = (lane & 1) ? p : v;       // Wa logit
                    const float vo = (lane & 1) ? v : p;       // Wb logit
                    const float e2 = __expf(2.f * ve);
                    const float gate = (1.f - 2.f / (e2 + 1.f)) * (1.f / (1.f + __expf(-vo)));
                    if (!(lane & 1)) {                         // even lane owns the pair
                        const int j = cl >> 1;
                        c0 += gate * sWcb[j*4+0]; c1 += gate * sWcb[j*4+1];
                        c2 += gate * sWcb[j*4+2]; c3 += gate * sWcb[j*4+3];
                    }
                }
                #pragma unroll
                for (int m = 1; m <= 8; m <<= 1) {
                    c0 += __shfl_xor(c0, m); c1 += __shfl_xor(c1, m);
                    c2 += __shfl_xor(c2, m); c3 += __shfl_xor(c3, m);
                }
                if ((lane & 15) == 0) {
                    const int row = bm0 + wm + mt*16 + lq*4 + reg;
                    if (row < NI) {
                        atomicAdd(&det_logit[(size_t)row*4+0], c0);
                        atomicAdd(&det_logit[(size_t)row*4+1], c1);
                        atomicAdd(&det_logit[(size_t)row*4+2], c2);
                        atomicAdd(&det_logit[(size_t)row*4+3], c3);
                    }
                }
            }
        }
    } else {
        if (wn == 0) {   // waves 0,2 hold the 19 real columns (512..530)
            #pragma unroll
            for (int mt = 0; mt < 4; ++mt)
                #pragma unroll
                for (int reg = 0; reg < 4; ++reg)
                    #pragma unroll
                    for (int nt = 0; nt < 2; ++nt) {
                        const int cl = nt*16 + lrow;
                        if (cl < 19) {
                            const int row = wm + mt*16 + lq*4 + reg;
                            slog[row * 20 + cl] = acc[mt][nt][reg] + sbias_blk[cl];
                        }
                    }
        }
        __syncthreads();
        if (tid < 128) {
            const int grow = bm0 + tid;
            if (grow < NI) {
                float L[19];
                #pragma unroll
                for (int q = 0; q < 19; ++q) L[q] = slog[tid * 20 + q];
                {   // cls softmax (cols 0..3)
                    float m = fmaxf(fmaxf(L[0], L[1]), fmaxf(L[2], L[3]));
                    float e0 = __expf(L[0]-m), e1 = __expf(L[1]-m), e2 = __expf(L[2]-m), e3 = __expf(L[3]-m);
                    const float inv = 1.f / (e0 + e1 + e2 + e3);
                    cls_score[(size_t)grow*4+0] = e0*inv; cls_score[(size_t)grow*4+1] = e1*inv;
                    cls_score[(size_t)grow*4+2] = e2*inv; cls_score[(size_t)grow*4+3] = e3*inv;
                }
                #pragma unroll
                for (int r = 0; r < 3; ++r) {
                    float m = L[4+5*r];
                    #pragma unroll
                    for (int e = 1; e < 5; ++e) m = fmaxf(m, L[4+5*r+e]);
                    float ev[5]; float s = 0.f;
                    #pragma unroll
                    for (int e = 0; e < 5; ++e) { ev[e] = __expf(L[4+5*r+e] - m); s += ev[e]; }
                    const float inv = 1.f / s;
                    float* dst = (r == 0) ? ref0 : ((r == 1) ? ref1 : out_ref2);
                    #pragma unroll
                    for (int e = 0; e < 5; ++e) dst[(size_t)grow*5+e] = ev[e] * inv;
                }
            }
        }
    }
}

// ================= kernel 3: det softmax denominator (no max: |logit| ~ 1) =================
__global__ __launch_bounds__(256) void det_sum_kernel(const float* __restrict__ det_logit,
                                                      float* __restrict__ det_sumexp)
{
    __shared__ float wsum[4][4];
    const int i = blockIdx.x * 256 + threadIdx.x;
    float p[4] = {0.f, 0.f, 0.f, 0.f};
    if (i < NI) {
        #pragma unroll
        for (int c = 0; c < 4; ++c) p[c] = __expf(det_logit[(size_t)i*4+c]);
    }
    #pragma unroll
    for (int c = 0; c < 4; ++c)
        #pragma unroll
        for (int m = 1; m < 64; m <<= 1) p[c] += __shfl_xor(p[c], m, 64);
    const int w = threadIdx.x >> 6;
    if ((threadIdx.x & 63) == 0) {
        #pragma unroll
        for (int c = 0; c < 4; ++c) wsum[w][c] = p[c];
    }
    __syncthreads();
    if (threadIdx.x < 4) {
        const int c = threadIdx.x;
        atomicAdd(&det_sumexp[c], wsum[0][c] + wsum[1][c] + wsum[2][c] + wsum[3][c]);
    }
}

// ================= kernel 4: final_score, mean, Y_prob partials, per-class min/max =================
__global__ __launch_bounds__(256) void final_kernel(const float* __restrict__ det_logit,
        const float* __restrict__ cls_score, const float* __restrict__ det_sumexp,
        float* __restrict__ out_fs, float* __restrict__ mean_sc, float* __restrict__ yprob_sum,
        unsigned* __restrict__ fs_min_enc, unsigned* __restrict__ fs_max_enc)
{
    __shared__ float ssum[4][4], smin[4][4], smax[4][4];
    const int i = blockIdx.x * 256 + threadIdx.x;
    const bool valid = i < NI;
    float f[4]; float tot = 0.f;
    #pragma unroll
    for (int c = 0; c < 4; ++c) {
        float v = 0.f;
        if (valid) {
            const float ds = __expf(det_logit[(size_t)i*4+c]) / det_sumexp[c];
            v = cls_score[(size_t)i*4+c] * ds;
            out_fs[(size_t)i*4+c] = v;
        }
        f[c] = v; tot += v;
    }
    if (valid) mean_sc[i] = 0.25f * tot;
    float sm[4], mn[4], mx[4];
    #pragma unroll
    for (int c = 0; c < 4; ++c) {
        sm[c] = f[c];
        mn[c] = valid ? f[c] : 3.4e38f;
        mx[c] = valid ? f[c] : -3.4e38f;
    }
    #pragma unroll
    for (int c = 0; c < 4; ++c)
        #pragma unroll
        for (int m = 1; m < 64; m <<= 1) {
            sm[c] += __shfl_xor(sm[c], m, 64);
            mn[c] = fminf(mn[c], __shfl_xor(mn[c], m, 64));
            mx[c] = fmaxf(mx[c], __shfl_xor(mx[c], m, 64));
        }
    const int w = threadIdx.x >> 6;
    if ((threadIdx.x & 63) == 0) {
        #pragma unroll
        for (int c = 0; c < 4; ++c) { ssum[w][c] = sm[c]; smin[w][c] = mn[c]; smax[w][c] = mx[c]; }
    }
    __syncthreads();
    if (threadIdx.x < 4) {
        const int c = threadIdx.x;
        float S = 0.f, MN = 3.4e38f, MX = -3.4e38f;
        #pragma unroll
        for (int w2 = 0; w2 < 4; ++w2) {
            S += ssum[w2][c]; MN = fminf(MN, smin[w2][c]); MX = fmaxf(MX, smax[w2][c]);
        }
        atomicAdd(&yprob_sum[c], S);
        atomicMin(&fs_min_enc[c], fenc(MN));
        atomicMax(&fs_max_enc[c], fenc(MX));
    }
}

// ================= kernel 5: Y_prob clip, Y_hat, thresholds, in_label =================
__global__ void scalars_kernel(const int* __restrict__ label, float* __restrict__ out,
                               float* __restrict__ ws_scal)
{
    if (blockIdx.x == 0 && threadIdx.x == 0) {
        float* sf = ws_scal; unsigned* su = (unsigned*)ws_scal; int* si = (int*)ws_scal;
        float best = -1.f; int arg = 0;
        for (int c = 0; c < 4; ++c) {
            float v = sf[SC_YPROB + c];
            v = fminf(fmaxf(v, 1e-10f), 1.f - 1e-10f);
            out[OUT_YP + c] = v;
            if (v > best) { best = v; arg = c; }
        }
        out[OUT_YH] = (float)arg;
        for (int c = 0; c < 4; ++c) {
            unsigned ue = su[SC_FSMIN + c], ux = su[SC_FSMAX + c];
            float mn = (ue & 0x80000000u) ? __uint_as_float(ue & 0x7FFFFFFFu) : __uint_as_float(~ue);
            float mx = (ux & 0x80000000u) ? __uint_as_float(ux & 0x7FFFFFFFu) : __uint_as_float(~ux);
            sf[SC_THR + c] = mn + 0.5f * (mx - mn);
        }
        const int l0 = label[0], l1 = label[1];
        for (int c = 0; c < 4; ++c) si[SC_INCL + c] = (l0 == c || l1 == c) ? 1 : 0;
        si[SC_INCL + 4] = 1;
    }
}

// ---- selection column accessor: b 0..3 fs, 4 mean(bottom), 5..9 ref0, 10..14 ref1
__device__ __forceinline__ float sel_value(int b, int i, const float* fs, const float* mean,
                                           const float* r0, const float* r1) {
    if (b < 4)  return fs[(size_t)i*4 + b];
    if (b == 4) return mean[i];
    if (b < 10) return r0[(size_t)i*5 + (b-5)];
    return r1[(size_t)i*5 + (b-10)];
}

// ================= kernel 6a/6c: radix histogram (level 0: u>>16, level 1: low16 of boundary bucket)
__global__ __launch_bounds__(256) void hist_kernel(const float* __restrict__ fs,
        const float* __restrict__ mean, const float* __restrict__ r0, const float* __restrict__ r1,
        unsigned* __restrict__ hist, const float* __restrict__ ws_scal, int level)
{
    const int b = blockIdx.x;
    const unsigned* su = (const unsigned*)ws_scal;
    unsigned* hh = hist + (size_t)b * 65536;
    const unsigned bA = (level == 1) ? su[SC_BUCKA + b] : 0u;
    for (int i = blockIdx.y * 256 + threadIdx.x; i < NI; i += 8 * 256) {
        const float v = sel_value(b, i, fs, mean, r0, r1);
        const unsigned u = fenc(b == 4 ? -v : v);
        if (level == 0) atomicAdd(&hh[u >> 16], 1u);
        else if ((u >> 16) == bA) atomicAdd(&hh[u & 0xFFFFu], 1u);
    }
}

// ================= kernel 6b/6d: suffix-scan 65536 bins -> boundary bucket / exact key; zeroes bins
__global__ __launch_bounds__(256) void scan_kernel(unsigned* __restrict__ hist,
                                                   float* __restrict__ ws_scal, int level)
{
    __shared__ unsigned tsum[256];
    const int b = blockIdx.x;
    unsigned* su = (unsigned*)ws_scal;
    unsigned* hh = hist + (size_t)b * 65536;
    const unsigned K = (level == 0) ? (unsigned)KSEL : su[SC_RESTK + b];
    const int t = threadIdx.x;
    const int base = t * 256;
    unsigned s = 0;
    for (int j = 0; j < 256; ++j) s += hh[base + j];
    tsum[t] = s;
    __syncthreads();
    for (int off = 1; off < 256; off <<= 1) {
        const unsigned v = tsum[t];
        const unsigned add = (t + off < 256) ? tsum[t + off] : 0u;
        __syncthreads();
        tsum[t] = v + add;
        __syncthreads();
    }
    unsigned running = (t + 1 < 256) ? tsum[t + 1] : 0u;   // count of bins >= base+256
    int found = -1; unsigned rem = 0;
    for (int j = 255; j >= 0; --j) {
        const unsigned hcnt = hh[base + j];
        if (found < 0 && running < K && running + hcnt >= K) { found = base + j; rem = K - running; }
        running += hcnt;
    }
    if (found >= 0) {
        if (level == 0) { su[SC_BUCKA + b] = (unsigned)found; su[SC_RESTK + b] = rem; }
        else            { su[SC_KTHK + b] = (su[SC_BUCKA + b] << 16) | (unsigned)found; }
    }
    for (int j = 0; j < 256; ++j) hh[base + j] = 0u;   // zero for reuse by level 1
}

// ================= kernel 6e: collect selected indices =================
__global__ __launch_bounds__(256) void collect_kernel(const float* __restrict__ fs,
        const float* __restrict__ mean, const float* __restrict__ r0, const float* __restrict__ r1,
        float* __restrict__ ws_scal, int* __restrict__ sel_idx)
{
    const int b = blockIdx.x;
    unsigned* su = (unsigned*)ws_scal; int* si = (int*)ws_scal; float* sf = ws_scal;
    const int c = (b < 4) ? b : ((b == 4) ? -1 : ((b < 10) ? b - 5 : b - 10));
    if (c >= 0 && c < 4 && !si[SC_INCL + c]) return;
    const unsigned kth = su[SC_KTHK + b];
    const float extra = (b < 4) ? sf[SC_THR + b] : 0.5f;
    for (int i = blockIdx.y * 256 + threadIdx.x; i < NI; i += 8 * 256) {
        const float v = sel_value(b, i, fs, mean, r0, r1);
        const unsigned u = fenc(b == 4 ? -v : v);
        const bool cond = (b == 4) ? (v < 0.5f) : (v > extra);
        if (u >= kth && cond) {
            const int pos = atomicAdd(&si[SC_CNT + b], 1);
            if (pos < KSEL) sel_idx[b * KSEL + pos] = i;
        }
    }
}

// ================= kernel 7: CE over selected candidates (one wave per slot) =================
__global__ __launch_bounds__(256) void ce_kernel(const float* __restrict__ h,
        const float* __restrict__ Wr, const float* __restrict__ br,
        const int* __restrict__ sel_idx, float* __restrict__ ws_scal)
{
    const int* si = (const int*)ws_scal;
    float* sf = ws_scal;
    const int lane = threadIdx.x & 63;
    const int wid = (blockIdx.x * blockDim.x + threadIdx.x) >> 6;
    const int nw = (gridDim.x * blockDim.x) >> 6;
    float l0a = 0.f, l1a = 0.f, l2a = 0.f;
    for (int slot = wid; slot < 15 * KSEL; slot += nw) {
        const int b = slot / KSEL;
        const int j = slot - b * KSEL;
        const int cnt = min(si[SC_CNT + b], KSEL);
        if (j >= cnt) continue;
        const int i = sel_idx[b * KSEL + j];
        const int g = (b < 5) ? 0 : ((b < 10) ? 1 : 2);
        const int tgt = (b < 4) ? b : ((b == 4) ? 4 : ((b < 10) ? (b - 5) : (b - 10)));
        const float* hr = h + (size_t)i * 512;
        const float* wr = Wr + (size_t)g * 512 * 5;
        const int d0 = lane * 8;
        const float4 va = *(const float4*)&hr[d0];
        const float4 vb = *(const float4*)&hr[d0 + 4];
        const float hv[8] = {va.x, va.y, va.z, va.w, vb.x, vb.y, vb.z, vb.w};
        float acc[5] = {0.f, 0.f, 0.f, 0.f, 0.f};
        #pragma unroll
        for (int t = 0; t < 8; ++t) {
            const float* row = wr + (size_t)(d0 + t) * 5;
            #pragma unroll
            for (int e = 0; e < 5; ++e) acc[e] += hv[t] * row[e];
        }
        #pragma unroll
        for (int e = 0; e < 5; ++e)
            #pragma unroll
            for (int m = 1; m < 64; m <<= 1) acc[e] += __shfl_xor(acc[e], m, 64);
        if (lane == 0) {
            float l[5];
            #pragma unroll
            for (int e = 0; e < 5; ++e) l[e] = acc[e] + br[g * 5 + e];
            float mx = l[0];
            #pragma unroll
            for (int e = 1; e < 5; ++e) mx = fmaxf(mx, l[e]);
            float s = 0.f;
            #pragma unroll
            for (int e = 0; e < 5; ++e) s += __expf(l[e] - mx);
            const float ce = logf(s) + mx - l[tgt];
            if (g == 0) l0a += ce; else if (g == 1) l1a += ce; else l2a += ce;
        }
    }
    if (lane == 0) {
        if (l0a != 0.f) atomicAdd(&sf[SC_NUM + 0], l0a);
        if (l1a != 0.f) atomicAdd(&sf[SC_NUM + 1], l1a);
        if (l2a != 0.f) atomicAdd(&sf[SC_NUM + 2], l2a);
    }
}

// ================= kernel 8: finalize instance_loss =================
__global__ void loss_kernel(const float* __restrict__ ws_scal, float* __restrict__ out)
{
    if (blockIdx.x == 0 && threadIdx.x == 0) {
        const int* si = (const int*)ws_scal;
        float loss = 0.f;
        for (int g = 0; g < 3; ++g) {
            int den = 0;
            for (int b = g * 5; b < g * 5 + 5; ++b) den += min(si[SC_CNT + b], KSEL);
            loss += ws_scal[SC_NUM + g] / (float)(den > 1 ? den : 1);
        }
        out[OUT_LOSS] = loss;
    }
}

// ================= launch =================
extern "C" void kernel_launch(void* const* d_in, const int* in_sizes, int n_in,
                              void* d_out, int out_size, void* d_ws, size_t ws_size,
                              hipStream_t stream)
{
    const float* h    = (const float*)d_in[0];
    const int*   lab  = (const int*)d_in[1];
    const float* Wa   = (const float*)d_in[2];
    const float* ba   = (const float*)d_in[3];
    const float* Wb   = (const float*)d_in[4];
    const float* bb   = (const float*)d_in[5];
    const float* Wc   = (const float*)d_in[6];
    const float* bc   = (const float*)d_in[7];
    const float* Wcls = (const float*)d_in[8];
    const float* bcls = (const float*)d_in[9];
    const float* Wr   = (const float*)d_in[10];
    const float* br   = (const float*)d_in[11];
    float* out = (float*)d_out;
    float* ws  = (float*)d_ws;

    float* det_logit = ws + OFF_DET;
    float* cls_score = ws + OFF_CLS;
    float* ref0      = ws + OFF_REF0;
    float* ref1      = ws + OFF_REF1;
    float* mean_sc   = ws + OFF_MEAN;
    unsigned short* wpT = (unsigned short*)(ws + OFF_WPT);
    float* scal = ws + OFF_SCAL;
    int*   sel_idx = (int*)(ws + OFF_SELIDX);
    unsigned* hist = (unsigned*)(ws + OFF_HIST);

    hipLaunchKernelGGL(prep_kernel, dim3(1280), dim3(256), 0, stream,
                       Wa, Wb, Wcls, Wr, ba, bb, bcls, br, bc, ws);
    hipLaunchKernelGGL(gemm_mfma, dim3(5, 782), dim3(256), 0, stream,
                       h, wpT, ws + OFF_BPACK, Wc,
                       det_logit, cls_score, ref0, ref1, out + OUT_REF);
    hipLaunchKernelGGL(det_sum_kernel, dim3(391), dim3(256), 0, stream,
                       det_logit, scal + SC_SUMEXP);
    hipLaunchKernelGGL(final_kernel, dim3(391), dim3(256), 0, stream,
                       det_logit, cls_score, scal + SC_SUMEXP,
                       out + OUT_FS, mean_sc, scal + SC_YPROB,
                       (unsigned*)(scal) + SC_FSMIN, (unsigned*)(scal) + SC_FSMAX);
    hipLaunchKernelGGL(scalars_kernel, dim3(1), dim3(64), 0, stream, lab, out, scal);
    hipLaunchKernelGGL(hist_kernel, dim3(15, 8), dim3(256), 0, stream,
                       out + OUT_FS, mean_sc, ref0, ref1, hist, scal, 0);
    hipLaunchKernelGGL(scan_kernel, dim3(15), dim3(256), 0, stream, hist, scal, 0);
    hipLaunchKernelGGL(hist_kernel, dim3(15, 8), dim3(256), 0, stream,
                       out + OUT_FS, mean_sc, ref0, ref1, hist, scal, 1);
    hipLaunchKernelGGL(scan_kernel, dim3(15), dim3(256), 0, stream, hist, scal, 1);
    hipLaunchKernelGGL(collect_kernel, dim3(15, 8), dim3(256), 0, stream,
                       out + OUT_FS, mean_sc, ref0, ref1, scal, sel_idx);
    hipLaunchKernelGGL(ce_kernel, dim3(240), dim3(256), 0, stream, h, Wr, br, sel_idx, scal);
    hipLaunchKernelGGL(loss_kernel, dim3(1), dim3(64), 0, stream, scal, out);
}

// Round 3
// 786.523 us; speedup vs baseline: 2.8658x; 1.3315x over previous
//
#include <hip/hip_runtime.h>
#include <math.h>

// ---------------- problem constants ----------------
#define NI    100000
#define KSEL  1000
#define NCOL2 640          // packed cols: 512 interleaved Wa/Wb pairs | 4 Wcls | 15 Wr | 109 pad
#define HBINS 2048         // radix histogram bins per selection column

// ---------------- d_out layout (floats) ----------------
#define OUT_FS   0
#define OUT_YP   400000
#define OUT_YH   400004
#define OUT_REF  400005
#define OUT_LOSS 900005

// ---------------- workspace layout (float offsets) ----------------
#define OFF_DET    0                 // det_logit N*4
#define OFF_CLS    400000            // cls_score N*4
#define OFF_REF0   800000            // softmax(h@Wr0+br0) N*5
#define OFF_REF1   1300000           // softmax(h@Wr1+br1) N*5
#define OFF_MEAN   1800000           // mean_score N
#define OFF_WPT    1900000           // bf16 packed W^T [640][512] = 327680 ushorts
#define OFF_BPACK  2063840           // packed bias [640]
#define OFF_SCAL   2064480           // 128 scalar slots
#define OFF_SELIDX 2064608           // 15*1000 ints
#define OFF_HIST   2079608           // 15*2048 u32

// scalar slots (index into u32/f32/i32 view of ws+OFF_SCAL)
#define SC_SUMEXP 0     // f[4] det softmax denominator
#define SC_YPROB  4     // f[4]
#define SC_FSMIN  8     // u[4] encoded min of final_score per class
#define SC_FSMAX  12    // u[4]
#define SC_THR    16    // f[4] norm-0.5 threshold on raw fs
#define SC_INCL   20    // i[5]
#define SC_NUM    25    // f[3] CE numerators
#define SC_CNT    28    // i[15] selected counts
#define SC_PREFIX 43    // u[15] accumulated radix prefix -> final = exact k-th key
#define SC_RESTK  58    // u[15] remaining k inside current prefix

typedef short short8 __attribute__((ext_vector_type(8)));
typedef float f32x4 __attribute__((ext_vector_type(4)));

__device__ __forceinline__ unsigned fenc(float x) {
    unsigned u = __float_as_uint(x);
    return (u & 0x80000000u) ? ~u : (u | 0x80000000u);
}
__device__ __forceinline__ unsigned short f2bf(float f) {
    unsigned u = __float_as_uint(f);
    return (unsigned short)((u + 0x7FFFu + ((u >> 16) & 1u)) >> 16);
}

// ================= kernel 1: pack weights bf16 col-major, biases, init scalars/hist =================
__global__ __launch_bounds__(256) void prep_kernel(
    const float* __restrict__ Wa, const float* __restrict__ Wb,
    const float* __restrict__ Wcls, const float* __restrict__ Wr,
    const float* __restrict__ ba, const float* __restrict__ bb,
    const float* __restrict__ bcls, const float* __restrict__ br,
    float* __restrict__ ws)
{
    const int tid0 = blockIdx.x * 256 + threadIdx.x;   // grid 1280*256 = 327680 threads
    unsigned short* wpT = (unsigned short*)(ws + OFF_WPT);
    if (tid0 < NCOL2 * 512) {
        const int c = tid0 >> 9, k = tid0 & 511;
        float v = 0.f;
        if (c < 512)      { const int j = c >> 1; v = (c & 1) ? Wb[k*256 + j] : Wa[k*256 + j]; }
        else if (c < 516)   v = Wcls[k*4 + (c - 512)];
        else if (c < 531) { const int q = c - 516; v = Wr[((q/5)*512 + k)*5 + (q%5)]; }
        wpT[tid0] = f2bf(v);
    }
    if (tid0 < NCOL2) {
        float v = 0.f; const int c = tid0;
        if (c < 512)      v = (c & 1) ? bb[c >> 1] : ba[c >> 1];
        else if (c < 516) v = bcls[c - 512];
        else if (c < 531) v = br[c - 516];
        ws[OFF_BPACK + c] = v;
    }
    if (tid0 < 128) {
        unsigned* su = (unsigned*)(ws + OFF_SCAL);
        unsigned v = 0u;
        if (tid0 >= SC_FSMIN && tid0 < SC_FSMIN + 4)   v = 0xFFFFFFFFu;
        if (tid0 >= SC_RESTK && tid0 < SC_RESTK + 15)  v = (unsigned)KSEL;
        su[tid0] = v;
    }
    unsigned* hist = (unsigned*)(ws + OFF_HIST);
    if (tid0 < 15 * HBINS) hist[tid0] = 0u;
}

// ================= kernel 2: bf16 MFMA GEMM, row-block resident, cb-loop inside =================
// grid 782 blocks x 256 thr. Each block owns 128 rows, loops over 5 column-blocks of 128.
// cb<4: gate pairs -> det partial into LDS sdet (no global atomics).
// cb==4: 19 small cols -> cls/ref softmaxes. End: det_logit write + sumexp partial.
__global__ __launch_bounds__(256) void gemm_mfma(
    const float* __restrict__ h, const unsigned short* __restrict__ wpT,
    const float* __restrict__ bpack, const float* __restrict__ Wc,
    const float* __restrict__ bc,
    float* __restrict__ det_logit, float* __restrict__ det_sumexp,
    float* __restrict__ cls_score, float* __restrict__ ref0,
    float* __restrict__ ref1, float* __restrict__ out_ref2)
{
    __shared__ unsigned short Als[128 * 40];   // [row][32k + pad8] bf16
    __shared__ unsigned short Bls[128 * 40];   // [col][32k + pad8] bf16
    __shared__ float sbias_blk[128];
    __shared__ float sWcb[256];
    __shared__ float slog[128 * 20];
    __shared__ float sdet[128][4];
    __shared__ float sred[4][4];

    const int tid = threadIdx.x;
    const int bm0 = blockIdx.x * 128;
    const int lane = tid & 63;
    const int w = tid >> 6;
    const int wm = (w >> 1) * 64, wn = (w & 1) * 64;
    const int lrow = lane & 15, lq = lane >> 4;

    if (tid < 128) { sdet[tid][0] = 0.f; sdet[tid][1] = 0.f; sdet[tid][2] = 0.f; sdet[tid][3] = 0.f; }

    for (int cb = 0; cb < 5; ++cb) {
        const int n0 = cb * 128;
        __syncthreads();   // prior epilogue done before overwriting sbias/sWcb/LDS tiles
        if (cb < 4) sWcb[tid] = Wc[(n0 >> 1) * 4 + tid];
        if (tid < 128) sbias_blk[tid] = bpack[n0 + tid];

        f32x4 acc[4][4];
        #pragma unroll
        for (int mt = 0; mt < 4; ++mt)
            #pragma unroll
            for (int nt = 0; nt < 4; ++nt) acc[mt][nt] = (f32x4)0.f;

        float4 aR[4]; uint4 bR[2];
        #pragma unroll
        for (int it = 0; it < 4; ++it) {
            const int q = tid + it*256, row = q >> 3, k0 = (q & 7) * 4, grow = bm0 + row;
            aR[it] = (grow < NI) ? *(const float4*)&h[(size_t)grow * 512 + k0]
                                 : make_float4(0.f, 0.f, 0.f, 0.f);
        }
        #pragma unroll
        for (int it = 0; it < 2; ++it) {
            const int q = tid + it*256, col = q >> 2, k0 = (q & 3) * 8;
            bR[it] = *(const uint4*)&wpT[(size_t)(n0 + col) * 512 + k0];
        }

        for (int kc = 0; kc < 512; kc += 32) {
            #pragma unroll
            for (int it = 0; it < 4; ++it) {
                const int q = tid + it*256, row = q >> 3, k0 = (q & 7) * 4;
                ushort4 pk;
                pk.x = f2bf(aR[it].x); pk.y = f2bf(aR[it].y);
                pk.z = f2bf(aR[it].z); pk.w = f2bf(aR[it].w);
                *(ushort4*)&Als[row * 40 + k0] = pk;
            }
            #pragma unroll
            for (int it = 0; it < 2; ++it) {
                const int q = tid + it*256, col = q >> 2, k0 = (q & 3) * 8;
                *(uint4*)&Bls[col * 40 + k0] = bR[it];
            }
            __syncthreads();
            const int kn = kc + 32;
            if (kn < 512) {   // prefetch next chunk (overlaps MFMA)
                #pragma unroll
                for (int it = 0; it < 4; ++it) {
                    const int q = tid + it*256, row = q >> 3, k0 = (q & 7) * 4, grow = bm0 + row;
                    aR[it] = (grow < NI) ? *(const float4*)&h[(size_t)grow * 512 + kn + k0]
                                         : make_float4(0.f, 0.f, 0.f, 0.f);
                }
                #pragma unroll
                for (int it = 0; it < 2; ++it) {
                    const int q = tid + it*256, col = q >> 2, k0 = (q & 3) * 8;
                    bR[it] = *(const uint4*)&wpT[(size_t)(n0 + col) * 512 + kn + k0];
                }
            }
            short8 af[4], bfr[4];
            #pragma unroll
            for (int mt = 0; mt < 4; ++mt) af[mt]  = *(const short8*)&Als[(wm + mt*16 + lrow) * 40 + lq*8];
            #pragma unroll
            for (int nt = 0; nt < 4; ++nt) bfr[nt] = *(const short8*)&Bls[(wn + nt*16 + lrow) * 40 + lq*8];
            #pragma unroll
            for (int mt = 0; mt < 4; ++mt)
                #pragma unroll
                for (int nt = 0; nt < 4; ++nt)
                    acc[mt][nt] = __builtin_amdgcn_mfma_f32_16x16x32_bf16(af[mt], bfr[nt], acc[mt][nt], 0, 0, 0);
            __syncthreads();
        }

        if (cb < 4) {
            // gated attention -> det partial; C/D layout col=lane&15, row=lq*4+reg
            #pragma unroll
            for (int mt = 0; mt < 4; ++mt) {
                #pragma unroll
                for (int reg = 0; reg < 4; ++reg) {
                    float c0 = 0.f, c1 = 0.f, c2 = 0.f, c3 = 0.f;
                    #pragma unroll
                    for (int nt = 0; nt < 4; ++nt) {
                        const int cl = wn + nt*16 + lrow;       // local col; parity == lane parity
                        const float v = acc[mt][nt][reg] + sbias_blk[cl];
                        const float p = __shfl_xor(v, 1);
                        const float ve = (lane & 1) ? p : v;    // Wa logit
                        const float vo = (lane & 1) ? v : p;    // Wb logit
                        const float e2 = __expf(2.f * ve);
                        const float gate = (1.f - 2.f / (e2 + 1.f)) * (1.f / (1.f + __expf(-vo)));
                        if (!(lane & 1)) {                      // even lane owns the pair
                            const int j = cl >> 1;
                            c0 += gate * sWcb[j*4+0]; c1 += gate * sWcb[j*4+1];
                            c2 += gate * sWcb[j*4+2]; c3 += gate * sWcb[j*4+3];
                        }
                    }
                    #pragma unroll
                    for (int m = 1; m <= 8; m <<= 1) {
                        c0 += __shfl_xor(c0, m); c1 += __shfl_xor(c1, m);
                        c2 += __shfl_xor(c2, m); c3 += __shfl_xor(c3, m);
                    }
                    if ((lane & 15) == 0) {
                        const int rl = wm + mt*16 + lq*4 + reg;
                        atomicAdd(&sdet[rl][0], c0); atomicAdd(&sdet[rl][1], c1);
                        atomicAdd(&sdet[rl][2], c2); atomicAdd(&sdet[rl][3], c3);
                    }
                }
            }
        } else {
            if (wn == 0) {   // waves 0,2 hold the 19 real columns (512..530)
                #pragma unroll
                for (int mt = 0; mt < 4; ++mt)
                    #pragma unroll
                    for (int reg = 0; reg < 4; ++reg)
                        #pragma unroll
                        for (int nt = 0; nt < 2; ++nt) {
                            const int cl = nt*16 + lrow;
                            if (cl < 19) {
                                const int row = wm + mt*16 + lq*4 + reg;
                                slog[row * 20 + cl] = acc[mt][nt][reg] + sbias_blk[cl];
                            }
                        }
            }
            __syncthreads();
            if (tid < 128) {
                const int grow = bm0 + tid;
                if (grow < NI) {
                    float L[19];
                    #pragma unroll
                    for (int q = 0; q < 19; ++q) L[q] = slog[tid * 20 + q];
                    {   // cls softmax (cols 0..3)
                        float m = fmaxf(fmaxf(L[0], L[1]), fmaxf(L[2], L[3]));
                        float e0 = __expf(L[0]-m), e1 = __expf(L[1]-m), e2 = __expf(L[2]-m), e3 = __expf(L[3]-m);
                        const float inv = 1.f / (e0 + e1 + e2 + e3);
                        cls_score[(size_t)grow*4+0] = e0*inv; cls_score[(size_t)grow*4+1] = e1*inv;
                        cls_score[(size_t)grow*4+2] = e2*inv; cls_score[(size_t)grow*4+3] = e3*inv;
                    }
                    #pragma unroll
                    for (int r = 0; r < 3; ++r) {
                        float m = L[4+5*r];
                        #pragma unroll
                        for (int e = 1; e < 5; ++e) m = fmaxf(m, L[4+5*r+e]);
                        float ev[5]; float s = 0.f;
                        #pragma unroll
                        for (int e = 0; e < 5; ++e) { ev[e] = __expf(L[4+5*r+e] - m); s += ev[e]; }
                        const float inv = 1.f / s;
                        float* dst = (r == 0) ? ref0 : ((r == 1) ? ref1 : out_ref2);
                        #pragma unroll
                        for (int e = 0; e < 5; ++e) dst[(size_t)grow*5+e] = ev[e] * inv;
                    }
                }
            }
        }
    }
    __syncthreads();

    // det_logit write + per-class exp-sum partial (fused det softmax denominator)
    float e0 = 0.f, e1 = 0.f, e2 = 0.f, e3 = 0.f;
    if (tid < 128) {
        const int grow = bm0 + tid;
        const float d0 = sdet[tid][0] + bc[0];
        const float d1 = sdet[tid][1] + bc[1];
        const float d2 = sdet[tid][2] + bc[2];
        const float d3 = sdet[tid][3] + bc[3];
        if (grow < NI) {
            float4 dv = make_float4(d0, d1, d2, d3);
            *(float4*)&det_logit[(size_t)grow * 4] = dv;
            e0 = __expf(d0); e1 = __expf(d1); e2 = __expf(d2); e3 = __expf(d3);
        }
    }
    #pragma unroll
    for (int m = 1; m < 64; m <<= 1) {
        e0 += __shfl_xor(e0, m); e1 += __shfl_xor(e1, m);
        e2 += __shfl_xor(e2, m); e3 += __shfl_xor(e3, m);
    }
    if (lane == 0) { sred[w][0] = e0; sred[w][1] = e1; sred[w][2] = e2; sred[w][3] = e3; }
    __syncthreads();
    if (tid < 4)
        atomicAdd(&det_sumexp[tid], sred[0][tid] + sred[1][tid] + sred[2][tid] + sred[3][tid]);
}

// ================= kernel 3: final_score, mean, Y_prob partials, per-class min/max =================
__global__ __launch_bounds__(256) void final_kernel(const float* __restrict__ det_logit,
        const float* __restrict__ cls_score, const float* __restrict__ det_sumexp,
        float* __restrict__ out_fs, float* __restrict__ mean_sc, float* __restrict__ yprob_sum,
        unsigned* __restrict__ fs_min_enc, unsigned* __restrict__ fs_max_enc)
{
    __shared__ float ssum[4][4], smin[4][4], smax[4][4];
    const int i = blockIdx.x * 256 + threadIdx.x;
    const bool valid = i < NI;
    float f[4]; float tot = 0.f;
    #pragma unroll
    for (int c = 0; c < 4; ++c) {
        float v = 0.f;
        if (valid) {
            const float ds = __expf(det_logit[(size_t)i*4+c]) / det_sumexp[c];
            v = cls_score[(size_t)i*4+c] * ds;
            out_fs[(size_t)i*4+c] = v;
        }
        f[c] = v; tot += v;
    }
    if (valid) mean_sc[i] = 0.25f * tot;
    float sm[4], mn[4], mx[4];
    #pragma unroll
    for (int c = 0; c < 4; ++c) {
        sm[c] = f[c];
        mn[c] = valid ? f[c] : 3.4e38f;
        mx[c] = valid ? f[c] : -3.4e38f;
    }
    #pragma unroll
    for (int c = 0; c < 4; ++c)
        #pragma unroll
        for (int m = 1; m < 64; m <<= 1) {
            sm[c] += __shfl_xor(sm[c], m, 64);
            mn[c] = fminf(mn[c], __shfl_xor(mn[c], m, 64));
            mx[c] = fmaxf(mx[c], __shfl_xor(mx[c], m, 64));
        }
    const int w = threadIdx.x >> 6;
    if ((threadIdx.x & 63) == 0) {
        #pragma unroll
        for (int c = 0; c < 4; ++c) { ssum[w][c] = sm[c]; smin[w][c] = mn[c]; smax[w][c] = mx[c]; }
    }
    __syncthreads();
    if (threadIdx.x < 4) {
        const int c = threadIdx.x;
        float S = 0.f, MN = 3.4e38f, MX = -3.4e38f;
        #pragma unroll
        for (int w2 = 0; w2 < 4; ++w2) {
            S += ssum[w2][c]; MN = fminf(MN, smin[w2][c]); MX = fmaxf(MX, smax[w2][c]);
        }
        atomicAdd(&yprob_sum[c], S);
        atomicMin(&fs_min_enc[c], fenc(MN));
        atomicMax(&fs_max_enc[c], fenc(MX));
    }
}

// ================= kernel 4: Y_prob clip, Y_hat, thresholds, in_label =================
__global__ void scalars_kernel(const int* __restrict__ label, float* __restrict__ out,
                               float* __restrict__ ws_scal)
{
    if (blockIdx.x == 0 && threadIdx.x == 0) {
        float* sf = ws_scal; unsigned* su = (unsigned*)ws_scal; int* si = (int*)ws_scal;
        float best = -1.f; int arg = 0;
        for (int c = 0; c < 4; ++c) {
            float v = sf[SC_YPROB + c];
            v = fminf(fmaxf(v, 1e-10f), 1.f - 1e-10f);
            out[OUT_YP + c] = v;
            if (v > best) { best = v; arg = c; }
        }
        out[OUT_YH] = (float)arg;
        for (int c = 0; c < 4; ++c) {
            unsigned ue = su[SC_FSMIN + c], ux = su[SC_FSMAX + c];
            float mn = (ue & 0x80000000u) ? __uint_as_float(ue & 0x7FFFFFFFu) : __uint_as_float(~ue);
            float mx = (ux & 0x80000000u) ? __uint_as_float(ux & 0x7FFFFFFFu) : __uint_as_float(~ux);
            sf[SC_THR + c] = mn + 0.5f * (mx - mn);
        }
        const int l0 = label[0], l1 = label[1];
        for (int c = 0; c < 4; ++c) si[SC_INCL + c] = (l0 == c || l1 == c) ? 1 : 0;
        si[SC_INCL + 4] = 1;
    }
}

// ---- selection column accessor: b 0..3 fs, 4 mean(bottom), 5..9 ref0, 10..14 ref1
__device__ __forceinline__ float sel_value(int b, int i, const float* fs, const float* mean,
                                           const float* r0, const float* r1) {
    if (b < 4)  return fs[(size_t)i*4 + b];
    if (b == 4) return mean[i];
    if (b < 10) return r0[(size_t)i*5 + (b-5)];
    return r1[(size_t)i*5 + (b-10)];
}

// ================= kernel 5: radix histogram pass (LDS-privatized), width<=11 bits =================
__global__ __launch_bounds__(256) void hist_kernel(const float* __restrict__ fs,
        const float* __restrict__ mean, const float* __restrict__ r0, const float* __restrict__ r1,
        unsigned* __restrict__ hist, const float* __restrict__ ws_scal, int shift, int width)
{
    const int b = blockIdx.x;
    const unsigned* su = (const unsigned*)ws_scal;
    const int* si = (const int*)ws_scal;
    const int c = (b < 4) ? b : ((b == 4) ? -1 : ((b < 10) ? b - 5 : b - 10));
    if (c >= 0 && !si[SC_INCL + c]) return;
    __shared__ unsigned lh[HBINS];
    const int nbins = 1 << width;
    for (int t = threadIdx.x; t < nbins; t += 256) lh[t] = 0u;
    __syncthreads();
    const int pb = shift + width;
    const unsigned prefix = su[SC_PREFIX + b];
    const unsigned mask = (unsigned)(nbins - 1);
    for (int i = blockIdx.y * 256 + threadIdx.x; i < NI; i += 8 * 256) {
        const float v = sel_value(b, i, fs, mean, r0, r1);
        const unsigned u = fenc(b == 4 ? -v : v);
        if (pb >= 32 || (u >> pb) == prefix)
            atomicAdd(&lh[(u >> shift) & mask], 1u);
    }
    __syncthreads();
    for (int t = threadIdx.x; t < nbins; t += 256)
        if (lh[t]) atomicAdd(&hist[(size_t)b * HBINS + t], lh[t]);
}

// ================= kernel 6: suffix-scan of bins -> extend prefix, update rem-k; zero bins =================
__global__ __launch_bounds__(256) void scan_kernel(unsigned* __restrict__ hist,
                                                   float* __restrict__ ws_scal, int width)
{
    __shared__ unsigned csum[256];
    const int b = blockIdx.x;
    unsigned* su = (unsigned*)ws_scal;
    unsigned* hh = hist + (size_t)b * HBINS;
    const int nbins = 1 << width;
    const int chunk = (nbins + 255) >> 8;
    unsigned s = 0;
    for (int j = 0; j < chunk; ++j) {
        const int idx = threadIdx.x * chunk + j;
        if (idx < nbins) s += hh[idx];
    }
    csum[threadIdx.x] = s;
    __syncthreads();
    if (threadIdx.x == 0) {
        const unsigned K = su[SC_RESTK + b];
        unsigned running = 0; unsigned found = 0; unsigned rem = K;
        int t;
        for (t = 255; t >= 0; --t) {
            if (running + csum[t] >= K) break;
            running += csum[t];
        }
        if (t < 0) t = 0;   // degenerate (excluded column): bins all zero
        for (int j = chunk - 1; j >= 0; --j) {
            const int idx = t * chunk + j;
            if (idx >= nbins) continue;
            const unsigned cc = hh[idx];
            if (running + cc >= K) { found = (unsigned)idx; rem = K - running; break; }
            running += cc;
        }
        su[SC_RESTK + b] = rem;
        su[SC_PREFIX + b] = (su[SC_PREFIX + b] << width) | found;
    }
    __syncthreads();
    for (int t2 = threadIdx.x; t2 < nbins; t2 += 256) hh[t2] = 0u;
}

// ================= kernel 7: collect selected indices =================
__global__ __launch_bounds__(256) void collect_kernel(const float* __restrict__ fs,
        const float* __restrict__ mean, const float* __restrict__ r0, const float* __restrict__ r1,
        float* __restrict__ ws_scal, int* __restrict__ sel_idx)
{
    const int b = blockIdx.x;
    unsigned* su = (unsigned*)ws_scal; int* si = (int*)ws_scal; float* sf = ws_scal;
    const int c = (b < 4) ? b : ((b == 4) ? -1 : ((b < 10) ? b - 5 : b - 10));
    if (c >= 0 && !si[SC_INCL + c]) return;
    const unsigned kth = su[SC_PREFIX + b];   // after 3 passes = exact k-th key
    const float extra = (b < 4) ? sf[SC_THR + b] : 0.5f;
    for (int i = blockIdx.y * 256 + threadIdx.x; i < NI; i += 8 * 256) {
        const float v = sel_value(b, i, fs, mean, r0, r1);
        const unsigned u = fenc(b == 4 ? -v : v);
        const bool cond = (b == 4) ? (v < 0.5f) : (v > extra);
        if (u >= kth && cond) {
            const int pos = atomicAdd(&si[SC_CNT + b], 1);
            if (pos < KSEL) sel_idx[b * KSEL + pos] = i;
        }
    }
}

// ================= kernel 8: CE over selected candidates (one wave per slot) =================
__global__ __launch_bounds__(256) void ce_kernel(const float* __restrict__ h,
        const float* __restrict__ Wr, const float* __restrict__ br,
        const int* __restrict__ sel_idx, float* __restrict__ ws_scal)
{
    const int* si = (const int*)ws_scal;
    float* sf = ws_scal;
    const int lane = threadIdx.x & 63;
    const int wid = (blockIdx.x * blockDim.x + threadIdx.x) >> 6;
    const int nw = (gridDim.x * blockDim.x) >> 6;
    float l0a = 0.f, l1a = 0.f, l2a = 0.f;
    for (int slot = wid; slot < 15 * KSEL; slot += nw) {
        const int b = slot / KSEL;
        const int j = slot - b * KSEL;
        const int cnt = min(si[SC_CNT + b], KSEL);
        if (j >= cnt) continue;
        const int i = sel_idx[b * KSEL + j];
        const int g = (b < 5) ? 0 : ((b < 10) ? 1 : 2);
        const int tgt = (b < 4) ? b : ((b == 4) ? 4 : ((b < 10) ? (b - 5) : (b - 10)));
        const float* hr = h + (size_t)i * 512;
        const float* wr = Wr + (size_t)g * 512 * 5;
        const int d0 = lane * 8;
        const float4 va = *(const float4*)&hr[d0];
        const float4 vb = *(const float4*)&hr[d0 + 4];
        const float hv[8] = {va.x, va.y, va.z, va.w, vb.x, vb.y, vb.z, vb.w};
        float acc[5] = {0.f, 0.f, 0.f, 0.f, 0.f};
        #pragma unroll
        for (int t = 0; t < 8; ++t) {
            const float* row = wr + (size_t)(d0 + t) * 5;
            #pragma unroll
            for (int e = 0; e < 5; ++e) acc[e] += hv[t] * row[e];
        }
        #pragma unroll
        for (int e = 0; e < 5; ++e)
            #pragma unroll
            for (int m = 1; m < 64; m <<= 1) acc[e] += __shfl_xor(acc[e], m, 64);
        if (lane == 0) {
            float l[5];
            #pragma unroll
            for (int e = 0; e < 5; ++e) l[e] = acc[e] + br[g * 5 + e];
            float mx = l[0];
            #pragma unroll
            for (int e = 1; e < 5; ++e) mx = fmaxf(mx, l[e]);
            float s = 0.f;
            #pragma unroll
            for (int e = 0; e < 5; ++e) s += __expf(l[e] - mx);
            const float ce = logf(s) + mx - l[tgt];
            if (g == 0) l0a += ce; else if (g == 1) l1a += ce; else l2a += ce;
        }
    }
    if (lane == 0) {
        if (l0a != 0.f) atomicAdd(&sf[SC_NUM + 0], l0a);
        if (l1a != 0.f) atomicAdd(&sf[SC_NUM + 1], l1a);
        if (l2a != 0.f) atomicAdd(&sf[SC_NUM + 2], l2a);
    }
}

// ================= kernel 9: finalize instance_loss =================
__global__ void loss_kernel(const float* __restrict__ ws_scal, float* __restrict__ out)
{
    if (blockIdx.x == 0 && threadIdx.x == 0) {
        const int* si = (const int*)ws_scal;
        float loss = 0.f;
        for (int g = 0; g < 3; ++g) {
            int den = 0;
            for (int b = g * 5; b < g * 5 + 5; ++b) den += min(si[SC_CNT + b], KSEL);
            loss += ws_scal[SC_NUM + g] / (float)(den > 1 ? den : 1);
        }
        out[OUT_LOSS] = loss;
    }
}

// ================= launch =================
extern "C" void kernel_launch(void* const* d_in, const int* in_sizes, int n_in,
                              void* d_out, int out_size, void* d_ws, size_t ws_size,
                              hipStream_t stream)
{
    const float* h    = (const float*)d_in[0];
    const int*   lab  = (const int*)d_in[1];
    const float* Wa   = (const float*)d_in[2];
    const float* ba   = (const float*)d_in[3];
    const float* Wb   = (const float*)d_in[4];
    const float* bb   = (const float*)d_in[5];
    const float* Wc   = (const float*)d_in[6];
    const float* bc   = (const float*)d_in[7];
    const float* Wcls = (const float*)d_in[8];
    const float* bcls = (const float*)d_in[9];
    const float* Wr   = (const float*)d_in[10];
    const float* br   = (const float*)d_in[11];
    float* out = (float*)d_out;
    float* ws  = (float*)d_ws;

    float* det_logit = ws + OFF_DET;
    float* cls_score = ws + OFF_CLS;
    float* ref0      = ws + OFF_REF0;
    float* ref1      = ws + OFF_REF1;
    float* mean_sc   = ws + OFF_MEAN;
    unsigned short* wpT = (unsigned short*)(ws + OFF_WPT);
    float* scal = ws + OFF_SCAL;
    int*   sel_idx = (int*)(ws + OFF_SELIDX);
    unsigned* hist = (unsigned*)(ws + OFF_HIST);

    hipLaunchKernelGGL(prep_kernel, dim3(1280), dim3(256), 0, stream,
                       Wa, Wb, Wcls, Wr, ba, bb, bcls, br, ws);
    hipLaunchKernelGGL(gemm_mfma, dim3(782), dim3(256), 0, stream,
                       h, wpT, ws + OFF_BPACK, Wc, bc,
                       det_logit, scal + SC_SUMEXP, cls_score, ref0, ref1, out + OUT_REF);
    hipLaunchKernelGGL(final_kernel, dim3(391), dim3(256), 0, stream,
                       det_logit, cls_score, scal + SC_SUMEXP,
                       out + OUT_FS, mean_sc, scal + SC_YPROB,
                       (unsigned*)(scal) + SC_FSMIN, (unsigned*)(scal) + SC_FSMAX);
    hipLaunchKernelGGL(scalars_kernel, dim3(1), dim3(64), 0, stream, lab, out, scal);
    hipLaunchKernelGGL(hist_kernel, dim3(15, 8), dim3(256), 0, stream,
                       out + OUT_FS, mean_sc, ref0, ref1, hist, scal, 21, 11);
    hipLaunchKernelGGL(scan_kernel, dim3(15), dim3(256), 0, stream, hist, scal, 11);
    hipLaunchKernelGGL(hist_kernel, dim3(15, 8), dim3(256), 0, stream,
                       out + OUT_FS, mean_sc, ref0, ref1, hist, scal, 10, 11);
    hipLaunchKernelGGL(scan_kernel, dim3(15), dim3(256), 0, stream, hist, scal, 11);
    hipLaunchKernelGGL(hist_kernel, dim3(15, 8), dim3(256), 0, stream,
                       out + OUT_FS, mean_sc, ref0, ref1, hist, scal, 0, 10);
    hipLaunchKernelGGL(scan_kernel, dim3(15), dim3(256), 0, stream, hist, scal, 10);
    hipLaunchKernelGGL(collect_kernel, dim3(15, 8), dim3(256), 0, stream,
                       out + OUT_FS, mean_sc, ref0, ref1, scal, sel_idx);
    hipLaunchKernelGGL(ce_kernel, dim3(240), dim3(256), 0, stream, h, Wr, br, sel_idx, scal);
    hipLaunchKernelGGL(loss_kernel, dim3(1), dim3(64), 0, stream, scal, out);
}